// Round 13
// baseline (221.054 us; speedup 1.0000x reference)
//
#include <hip/hip_runtime.h>
#include <hip/hip_bf16.h>

#define DEVI __device__ __forceinline__

typedef float f32x4 __attribute__((ext_vector_type(4)));
typedef short s16x8 __attribute__((ext_vector_type(8)));

constexpr int T_ = 64;    // window
constexpr int F_ = 16;    // features
constexpr int H_ = 128;   // hidden
constexpr int NSEQ_ = 1024;
constexpr int NB_ = 2;    // sequences per block (MFMA N cols 2..15 don't-care)
constexpr int NBLK_ = NSEQ_ / NB_;  // 512 blocks -> 2 blocks/CU co-scheduled

DEVI float sigmoidf_(float x) { return 1.0f / (1.0f + __expf(-x)); }
DEVI float tanhf_(float x) {
    float a = fabsf(x);
    float e = __expf(-2.0f * a);
    return copysignf((1.0f - e) / (1.0f + e), x);
}
DEVI ushort f2h(float f) {              // fp32 -> fp16 bits
    _Float16 h = (_Float16)f;
    ushort b; __builtin_memcpy(&b, &h, 2); return b;
}
DEVI float h2f(ushort b) {
    _Float16 h; __builtin_memcpy(&h, &b, 2); return (float)h;
}

#define MFMA16(A,B,C) __builtin_amdgcn_mfma_f32_16x16x32_f16((A),(B),(C),0,0,0)

// LDS pool, phase-aliased (52768 B; 2 blocks/CU -> 105 KB < 160 KB):
//  recurrence: xh ushort[2][1032] @0 (4128B)  [x fp16, 2 real seqs]
//              hA @8320 (5376B), hB @13696 (5376B)   [h fp16 ping-pong, 16 rows]
//  epilogue (recurrence regions dead):
//              w1h ushort[128][140] @0 (35840B)
//              a2s  float[16][128]  @35840
//              logitb float[16][64] @44032
//              alph   float[16][64] @48128
//              wab    float[132]    @52224
constexpr int XSTR = 1032;
constexpr int HSTR = 168;   // f16 per h row (336 B)
constexpr int OFF_HA  = 8320, OFF_HB = 13696;
constexpr int OFF_A2S = 35840, OFF_LOG = 44032, OFF_ALPH = 48128, OFF_WAB = 52224;
constexpr int POOL_BYTES = 52768;

__global__ __launch_bounds__(512, 4)   // 4 waves/EU min -> VGPR cap 128
void alphastock_main(const float* __restrict__ x,
                     const float* __restrict__ W_ih, const float* __restrict__ W_hh,
                     const float* __restrict__ b_ih, const float* __restrict__ b_hh,
                     const float* __restrict__ w1, const float* __restrict__ b1,
                     const float* __restrict__ w2, const float* __restrict__ b2,
                     const float* __restrict__ wa, const float* __restrict__ ba,
                     const float* __restrict__ wq, const float* __restrict__ bq,
                     const float* __restrict__ wk, const float* __restrict__ bk,
                     const float* __restrict__ wvm, const float* __restrict__ bv,
                     ushort* __restrict__ rep,   // [1024][64][128] fp16 ws
                     float* __restrict__ qout, float* __restrict__ kout,
                     float* __restrict__ vout)
{
    __shared__ alignas(16) char pool_[POOL_BYTES];
    ushort* xh    = (ushort*)pool_;
    ushort* hA    = (ushort*)(pool_ + OFF_HA);
    ushort* hB    = (ushort*)(pool_ + OFF_HB);
    ushort* w1h   = (ushort*)pool_;                    // epilogue alias
    float*  a2s   = (float*)(pool_ + OFF_A2S);
    float*  logitb= (float*)(pool_ + OFF_LOG);
    float*  alph  = (float*)(pool_ + OFF_ALPH);
    float*  wab   = (float*)(pool_ + OFF_WAB);

    const int tid  = threadIdx.x;
    const int wv   = tid >> 6;        // wave 0..7
    const int lane = tid & 63;
    const int lN   = lane & 15;       // frag col (seq; real 0..1) / A-row
    const int lK   = lane >> 4;       // k-group 0..3
    const int nb   = blockIdx.x * NB_;

    // ---- prologue: zero BOTH h buffers; stage x (2 seqs) -> LDS fp16 ----
    for (int i = tid; i < 10752 / 4; i += 512)
        ((unsigned*)(pool_ + OFF_HA))[i] = 0;          // hA + hB (contiguous)
    for (int idx = tid; idx < NB_ * T_ * F_; idx += 512) {   // 2048
        int s = idx >> 10, rem = idx & 1023;                 // rem = t*16+f
        xh[s * XSTR + rem] = f2h(x[(size_t)(nb + s) * 1024 + rem]);
    }

    // ---- A-frags Whh fp16: row ra = 128g + 16wv + lN; k = ks*32 + lK*8 + i
    s16x8 wf[4][4];
    #pragma unroll
    for (int g = 0; g < 4; ++g) {
        const int ra = 128 * g + 16 * wv + lN;
        #pragma unroll
        for (int ks = 0; ks < 4; ++ks) {
            const float4* p = (const float4*)(W_hh + (size_t)ra * 128 + ks * 32 + lK * 8);
            float4 v0 = p[0], v1 = p[1];
            float w[8] = {v0.x,v0.y,v0.z,v0.w, v1.x,v1.y,v1.z,v1.w};
            #pragma unroll
            for (int i = 0; i < 8; ++i) wf[g][ks][i] = (short)f2h(w[i]);
        }
    }
    // Wih fp16 frags: K=16 padded to 32; lanes lK>=2 get zero A.
    s16x8 wif[4];
    #pragma unroll
    for (int g = 0; g < 4; ++g) {
        const int ra = 128 * g + 16 * wv + lN;
        const float4* p = (const float4*)(W_ih + (size_t)ra * 16 + (lK & 1) * 8);
        float4 v0 = p[0], v1 = p[1];
        float w[8] = {v0.x,v0.y,v0.z,v0.w, v1.x,v1.y,v1.z,v1.w};
        #pragma unroll
        for (int i = 0; i < 8; ++i)
            wif[g][i] = (short)((lK < 2) ? f2h(w[i]) : 0);
    }
    // bias: 4 scalars per lane, added AFTER the gather (cell jglob = 16wv+jloc)
    const int jloc = lane >> 2;             // 0..15
    const int sloc = lane & 3;              // 0..3 (real 0..1)
    float biasc[4];
    #pragma unroll
    for (int g = 0; g < 4; ++g) {
        int rr = 128 * g + 16 * wv + jloc;
        biasc[g] = b_ih[rr] + b_hh[rr];
    }
    __syncthreads();

    // ---- recurrent loop ----
    // Gather: lane L owns cell (jloc = L>>2, sloc = L&3); src lane
    // (L&3) + 16*(L>>4), register r = (L>>2)&3. One cell update per lane.
    const int hoff = lN * HSTR;
    const ushort* xrow = xh + (lN & 1) * XSTR + (lK & 1) * 8;
    const int srcLane = (lane & 3) + 16 * (lane >> 4);
    const int rsel    = (lane >> 2) & 3;
    const int hwoff   = sloc * HSTR + 16 * wv + jloc;   // h write slot (2B)
    ushort* repL = rep + ((size_t)(nb + (sloc & 1)) * T_) * H_ + 16 * wv + jloc;
    const f32x4 zc = {0.f, 0.f, 0.f, 0.f};
    float cst = 0.f;
    #pragma unroll 1
    for (int tb = 0; tb < 32; ++tb) {
        #pragma unroll
        for (int u = 0; u < 2; ++u) {
            const int t = 2 * tb + u;
            s16x8 bx = *(const s16x8*)(xrow + t * 16);

            f32x4 acc0 = MFMA16(wif[0], bx, zc);
            f32x4 acc1 = MFMA16(wif[1], bx, zc);
            f32x4 acc2 = MFMA16(wif[2], bx, zc);
            f32x4 acc3 = MFMA16(wif[3], bx, zc);

            const ushort* hh = (u & 1) ? hB : hA;     // compile-time select
            #pragma unroll
            for (int ks = 0; ks < 4; ++ks) {
                s16x8 bh = *(const s16x8*)(hh + hoff + ks * 32 + lK * 8);
                acc0 = MFMA16(wf[0][ks], bh, acc0);
                acc1 = MFMA16(wf[1][ks], bh, acc1);
                acc2 = MFMA16(wf[2][ks], bh, acc2);
                acc3 = MFMA16(wf[3][ks], bh, acc3);
            }

            // redistribute the 4 gate values for this lane's (jloc, sloc)
            float t0, t1, t2, t3, gi, gf, gg, go;
            t0 = __shfl(acc0[0], srcLane); t1 = __shfl(acc0[1], srcLane);
            t2 = __shfl(acc0[2], srcLane); t3 = __shfl(acc0[3], srcLane);
            gi = (rsel < 2) ? (rsel ? t1 : t0) : ((rsel == 2) ? t2 : t3);
            t0 = __shfl(acc1[0], srcLane); t1 = __shfl(acc1[1], srcLane);
            t2 = __shfl(acc1[2], srcLane); t3 = __shfl(acc1[3], srcLane);
            gf = (rsel < 2) ? (rsel ? t1 : t0) : ((rsel == 2) ? t2 : t3);
            t0 = __shfl(acc2[0], srcLane); t1 = __shfl(acc2[1], srcLane);
            t2 = __shfl(acc2[2], srcLane); t3 = __shfl(acc2[3], srcLane);
            gg = (rsel < 2) ? (rsel ? t1 : t0) : ((rsel == 2) ? t2 : t3);
            t0 = __shfl(acc3[0], srcLane); t1 = __shfl(acc3[1], srcLane);
            t2 = __shfl(acc3[2], srcLane); t3 = __shfl(acc3[3], srcLane);
            go = (rsel < 2) ? (rsel ? t1 : t0) : ((rsel == 2) ? t2 : t3);

            // ONE cell update per lane (bias folded here)
            float ii = sigmoidf_(gi + biasc[0]);
            float ff = sigmoidf_(gf + biasc[1]);
            float gt = tanhf_  (gg + biasc[2]);
            float oo = sigmoidf_(go + biasc[3]);
            float c  = ff * cst + ii * gt;
            cst = c;
            ushort hb = f2h(oo * tanhf_(c));

            ushort* hw = (u & 1) ? hA : hB;           // write the OTHER buffer
            hw[hwoff] = hb;                           // 2B LDS write
            if (sloc < NB_)
                repL[(size_t)t * H_] = hb;            // 2B global store
            __syncthreads();
        }
    }

    // ================= epilogue (2 seqs in this block) =================
    // E0: stage w1 (fp16, stride 140) + wa/ba  (recurrence LDS dead)
    for (int idx = tid; idx < 128 * 128; idx += 512) {
        int o = idx >> 7, k = idx & 127;
        w1h[o * 140 + k] = f2h(w1[idx]);
    }
    if (tid < 128) wab[tid] = wa[tid];
    if (tid == 128) wab[128] = ba[0];
    __syncthreads();

    // E1: a2[s][o] = h63 @ w2^T + b1 + b2  (wave 0; A rows >=2 dup of row&1)
    if (wv == 0) {
        s16x8 ar[4];
        #pragma unroll
        for (int ks = 0; ks < 4; ++ks)
            ar[ks] = *(const s16x8*)(rep + ((size_t)(nb + (lN & 1)) * T_ + 63) * H_ + ks * 32 + lK * 8);
        #pragma unroll
        for (int nt = 0; nt < 8; ++nt) {
            f32x4 acc = {0.f,0.f,0.f,0.f};
            const int o = 16 * nt + lN;
            #pragma unroll
            for (int ks = 0; ks < 4; ++ks) {
                const float4* p = (const float4*)(w2 + (size_t)o * 128 + ks * 32 + lK * 8);
                float4 v0 = p[0], v1 = p[1];
                s16x8 bb;
                bb[0]=(short)f2h(v0.x); bb[1]=(short)f2h(v0.y); bb[2]=(short)f2h(v0.z); bb[3]=(short)f2h(v0.w);
                bb[4]=(short)f2h(v1.x); bb[5]=(short)f2h(v1.y); bb[6]=(short)f2h(v1.z); bb[7]=(short)f2h(v1.w);
                acc = MFMA16(ar[ks], bb, acc);
            }
            float bb12 = b1[o] + b2[o];
            #pragma unroll
            for (int r = 0; r < 4; ++r)
                a2s[(4 * lK + r) * 128 + o] = acc[r] + bb12;   // seq = 4lK+r
        }
    }
    __syncthreads();

    // E2: logits[t] = sum_o wa[o]*tanh((rep @ w1^T)[t][o] + a2[o])
    // 4 waves per seq: seq = wv>>2, mt = wv&3
    {
        const int seq = wv >> 2;
        const int mt  = wv & 3;
        s16x8 ar[4];
        #pragma unroll
        for (int ks = 0; ks < 4; ++ks)
            ar[ks] = *(const s16x8*)(rep + ((size_t)(nb + seq) * T_ + 16 * mt + lN) * H_ + ks * 32 + lK * 8);
        float part[4] = {0.f,0.f,0.f,0.f};
        #pragma unroll
        for (int nt = 0; nt < 8; ++nt) {
            f32x4 acc = {0.f,0.f,0.f,0.f};
            #pragma unroll
            for (int ks = 0; ks < 4; ++ks)
                acc = MFMA16(ar[ks],
                             *(const s16x8*)(w1h + (lN + 16 * nt) * 140 + ks * 32 + lK * 8),
                             acc);
            const int o = lN + 16 * nt;
            const float wao = wab[o];
            const float a2o = a2s[seq * 128 + o];
            #pragma unroll
            for (int r = 0; r < 4; ++r)
                part[r] += wao * tanhf_(acc[r] + a2o);
        }
        #pragma unroll
        for (int r = 0; r < 4; ++r) {
            part[r] += __shfl_xor(part[r], 1);
            part[r] += __shfl_xor(part[r], 2);
            part[r] += __shfl_xor(part[r], 4);
            part[r] += __shfl_xor(part[r], 8);
        }
        if (lN == 0) {
            float4 st; st.x = part[0]; st.y = part[1]; st.z = part[2]; st.w = part[3];
            *(float4*)(logitb + seq * 64 + 16 * mt + 4 * lK) = st;  // t = 16mt+4lK+r
        }
    }
    __syncthreads();

    // E3: softmax over 64 logits, seq = wv (waves 0..1)
    if (wv < NB_) {
        const int seq = wv;
        float vl = logitb[seq * 64 + lane] + wab[128];
        float m = vl;
        #pragma unroll
        for (int off = 1; off < 64; off <<= 1) m = fmaxf(m, __shfl_xor(m, off));
        float e = __expf(vl - m);
        float ss = e;
        #pragma unroll
        for (int off = 1; off < 64; off <<= 1) ss += __shfl_xor(ss, off);
        alph[seq * 64 + lane] = e / ss;
    }
    __syncthreads();

    // E4: stock_rep[s][h] = sum_t alpha * rep  (fp32, into a2s alias)
    {
        const int s = (tid >> 7) & (NB_ - 1);      // dup for upper half
        const int o = tid & 127;
        float acc = 0.f;
        const ushort* rp = rep + (size_t)(nb + s) * T_ * H_ + o;
        #pragma unroll 8
        for (int t = 0; t < T_; ++t)
            acc += alph[s * 64 + t] * h2f(rp[(size_t)t * H_]);
        __syncthreads();                           // a2s readers (E2) done
        if (tid < NB_ * 128)
            a2s[s * 128 + o] = acc;
    }
    __syncthreads();

    // E5: q,k,v = sr @ W^T + b  (fp32 VALU; one seq per thread-group)
    {
        const float* sr = a2s;
        const int o = tid & 127, sg = tid >> 7;    // sg 0..3, real 0..1
        if (sg < NB_) {
            float aq = 0.f, ak = 0.f, av = 0.f;
            for (int k = 0; k < 128; k += 4) {
                float4 q4 = *(const float4*)(wq  + (size_t)o * 128 + k);
                float4 k4 = *(const float4*)(wk  + (size_t)o * 128 + k);
                float4 v4 = *(const float4*)(wvm + (size_t)o * 128 + k);
                float4 s4 = *(const float4*)(sr + sg * 128 + k);
                aq += q4.x*s4.x + q4.y*s4.y + q4.z*s4.z + q4.w*s4.w;
                ak += k4.x*s4.x + k4.y*s4.y + k4.z*s4.z + k4.w*s4.w;
                av += v4.x*s4.x + v4.y*s4.y + v4.z*s4.z + v4.w*s4.w;
            }
            qout[(size_t)(nb + sg) * H_ + o] = aq + bq[o];
            kout[(size_t)(nb + sg) * H_ + o] = ak + bk[o];
            vout[(size_t)(nb + sg) * H_ + o] = av + bv[o];
        }
    }
}

// Cross-asset attention: one block per (b, m) query row, 256 threads. fp32 out.
__global__ __launch_bounds__(256, 4)
void caan(const float* __restrict__ qb, const float* __restrict__ kb,
          const float* __restrict__ vb, const float* __restrict__ ww,
          const float* __restrict__ bw, float* __restrict__ out)
{
    __shared__ alignas(16) float qs[H_];
    __shared__ alignas(16) float sc[512];
    __shared__ alignas(16) float red[8];
    __shared__ alignas(16) float pv[2][H_];

    const int n   = blockIdx.x;
    const int b   = n >> 9;
    const int tid = threadIdx.x;

    if (tid < H_) qs[tid] = qb[n * H_ + tid];
    __syncthreads();

    const float scale = 0.08838834764831845f;  // 1/sqrt(128)
    float s0raw = 0.f, s1raw = 0.f;
    #pragma unroll
    for (int r = 0; r < 2; ++r) {
        const int j = tid + r * 256;
        const float4* kp = (const float4*)(kb + (size_t)(b * 512 + j) * H_);
        const float4* qp = (const float4*)qs;
        float c0=0.f,c1=0.f,c2=0.f,c3=0.f;
        #pragma unroll
        for (int i = 0; i < 32; ++i) {
            float4 kv = kp[i], qv = qp[i];
            c0 += kv.x*qv.x; c1 += kv.y*qv.y; c2 += kv.z*qv.z; c3 += kv.w*qv.w;
        }
        float sres = ((c0 + c1) + (c2 + c3)) * scale;
        if (r == 0) s0raw = sres; else s1raw = sres;
    }

    float m = fmaxf(s0raw, s1raw);
    #pragma unroll
    for (int off = 1; off < 64; off <<= 1) m = fmaxf(m, __shfl_xor(m, off));
    if ((tid & 63) == 0) red[tid >> 6] = m;
    __syncthreads();
    m = fmaxf(fmaxf(red[0], red[1]), fmaxf(red[2], red[3]));
    float e0 = __expf(s0raw - m), e1 = __expf(s1raw - m);
    sc[tid] = e0; sc[tid + 256] = e1;
    float lsum = e0 + e1;
    #pragma unroll
    for (int off = 1; off < 64; off <<= 1) lsum += __shfl_xor(lsum, off);
    if ((tid & 63) == 0) red[4 + (tid >> 6)] = lsum;
    __syncthreads();
    const float inv = 1.0f / ((red[4] + red[5]) + (red[6] + red[7]));

    const int o  = tid & (H_ - 1);
    const int jh = tid >> 7;
    const float* vp = vb + (size_t)(b * 512 + jh * 256) * H_ + o;
    float a0=0.f,a1=0.f,a2=0.f,a3=0.f;
    for (int j = 0; j < 256; j += 4) {
        a0 += sc[jh*256 + j + 0] * vp[(size_t)(j + 0) * H_];
        a1 += sc[jh*256 + j + 1] * vp[(size_t)(j + 1) * H_];
        a2 += sc[jh*256 + j + 2] * vp[(size_t)(j + 2) * H_];
        a3 += sc[jh*256 + j + 3] * vp[(size_t)(j + 3) * H_];
    }
    pv[jh][o] = (a0 + a1) + (a2 + a3);
    __syncthreads();
    if (tid < H_) {
        float s = (pv[0][tid] + pv[1][tid]) * inv * ww[tid];
        s += __shfl_xor(s, 1);  s += __shfl_xor(s, 2);  s += __shfl_xor(s, 4);
        s += __shfl_xor(s, 8);  s += __shfl_xor(s, 16); s += __shfl_xor(s, 32);
        if ((tid & 63) == 0) red[tid >> 6] = s;
    }
    __syncthreads();
    if (tid == 0) out[n] = red[0] + red[1] + bw[0];
}

extern "C" void kernel_launch(void* const* d_in, const int* in_sizes, int n_in,
                              void* d_out, int out_size, void* d_ws, size_t ws_size,
                              hipStream_t stream)
{
    const float* x    = (const float*)d_in[0];
    const float* W_ih = (const float*)d_in[1];
    const float* W_hh = (const float*)d_in[2];
    const float* b_ih = (const float*)d_in[3];
    const float* b_hh = (const float*)d_in[4];
    const float* w1   = (const float*)d_in[5];
    const float* b1   = (const float*)d_in[6];
    const float* w2   = (const float*)d_in[7];
    const float* b2   = (const float*)d_in[8];
    const float* wa   = (const float*)d_in[9];
    const float* ba   = (const float*)d_in[10];
    const float* wq   = (const float*)d_in[11];
    const float* bq   = (const float*)d_in[12];
    const float* wk   = (const float*)d_in[13];
    const float* bk   = (const float*)d_in[14];
    const float* wv   = (const float*)d_in[15];
    const float* bv   = (const float*)d_in[16];
    const float* ww   = (const float*)d_in[17];
    const float* bw   = (const float*)d_in[18];

    float* ws   = (float*)d_ws;
    float* qbuf = ws;                              // 1024*128 f32
    float* kbuf = ws + (size_t)NSEQ_ * H_;
    float* vbuf = ws + (size_t)2 * NSEQ_ * H_;
    ushort* rep = (ushort*)(ws + (size_t)3 * NSEQ_ * H_);        // 16 MB fp16

    alphastock_main<<<NBLK_, 512, 0, stream>>>(x, W_ih, W_hh, b_ih, b_hh,
                                               w1, b1, w2, b2, wa, ba,
                                               wq, bq, wk, bk, wv, bv,
                                               rep, qbuf, kbuf, vbuf);
    caan<<<NSEQ_, 256, 0, stream>>>(qbuf, kbuf, vbuf, ww, bw, (float*)d_out);
}

// Round 14
// 173.741 us; speedup vs baseline: 1.2723x; 1.2723x over previous
//
#include <hip/hip_runtime.h>
#include <hip/hip_bf16.h>

#define DEVI __device__ __forceinline__

typedef float f32x4 __attribute__((ext_vector_type(4)));
typedef short s16x8 __attribute__((ext_vector_type(8)));

constexpr int T_ = 64;    // window
constexpr int F_ = 16;    // features
constexpr int H_ = 128;   // hidden
constexpr int NSEQ_ = 1024;
constexpr int NB_ = 4;    // sequences per block (MFMA N cols 4..15 don't-care)
constexpr int NBLK_ = NSEQ_ / NB_;  // 256 blocks -> every CU gets work

DEVI float sigmoidf_(float x) { return 1.0f / (1.0f + __expf(-x)); }
DEVI float tanhf_(float x) {
    float a = fabsf(x);
    float e = __expf(-2.0f * a);
    return copysignf((1.0f - e) / (1.0f + e), x);
}
DEVI ushort f2h(float f) {              // fp32 -> fp16 bits
    _Float16 h = (_Float16)f;
    ushort b; __builtin_memcpy(&b, &h, 2); return b;
}
DEVI float h2f(ushort b) {
    _Float16 h; __builtin_memcpy(&h, &b, 2); return (float)h;
}

#define MFMA16(A,B,C) __builtin_amdgcn_mfma_f32_16x16x32_f16((A),(B),(C),0,0,0)

// In-loop barrier: order LDS ops only (lgkmcnt), do NOT drain vmcnt.
// The rep global stores issued in the loop are read only after the
// epilogue's full __syncthreads() (which drains vmcnt(0)). Saves a
// ~300-500 cyc L2 store-ack on every step's critical path.
#define BAR_LDS() asm volatile("s_waitcnt lgkmcnt(0)\n\ts_barrier" ::: "memory")

// LDS pool, phase-aliased (52768 B):
//  recurrence: xh ushort[4][1032] @0 (8256B)  [x fp16, 4 real seqs]
//              hA @8320 (5376B), hB @13696 (5376B)   [h fp16 ping-pong, 16 rows]
//  epilogue (recurrence regions dead):
//              w1h ushort[128][140] @0 (35840B)
//              a2s  float[16][128]  @35840
//              logitb float[16][64] @44032
//              alph   float[16][64] @48128
//              wab    float[132]    @52224
constexpr int XSTR = 1032;
constexpr int HSTR = 168;   // f16 per h row (336 B)
constexpr int OFF_HA  = 8320, OFF_HB = 13696;
constexpr int OFF_A2S = 35840, OFF_LOG = 44032, OFF_ALPH = 48128, OFF_WAB = 52224;
constexpr int POOL_BYTES = 52768;

__global__ __launch_bounds__(512, 2)
void alphastock_main(const float* __restrict__ x,
                     const float* __restrict__ W_ih, const float* __restrict__ W_hh,
                     const float* __restrict__ b_ih, const float* __restrict__ b_hh,
                     const float* __restrict__ w1, const float* __restrict__ b1,
                     const float* __restrict__ w2, const float* __restrict__ b2,
                     const float* __restrict__ wa, const float* __restrict__ ba,
                     const float* __restrict__ wq, const float* __restrict__ bq,
                     const float* __restrict__ wk, const float* __restrict__ bk,
                     const float* __restrict__ wvm, const float* __restrict__ bv,
                     ushort* __restrict__ rep,   // [1024][64][128] fp16 ws
                     float* __restrict__ qout, float* __restrict__ kout,
                     float* __restrict__ vout)
{
    __shared__ alignas(16) char pool_[POOL_BYTES];
    ushort* xh    = (ushort*)pool_;
    ushort* hA    = (ushort*)(pool_ + OFF_HA);
    ushort* hB    = (ushort*)(pool_ + OFF_HB);
    ushort* w1h   = (ushort*)pool_;                    // epilogue alias
    float*  a2s   = (float*)(pool_ + OFF_A2S);
    float*  logitb= (float*)(pool_ + OFF_LOG);
    float*  alph  = (float*)(pool_ + OFF_ALPH);
    float*  wab   = (float*)(pool_ + OFF_WAB);

    const int tid  = threadIdx.x;
    const int wv   = tid >> 6;        // wave 0..7
    const int lane = tid & 63;
    const int lN   = lane & 15;       // frag col (seq; real 0..3) / A-row
    const int lK   = lane >> 4;       // k-group 0..3
    const int nb   = blockIdx.x * NB_;

    // ---- prologue: zero BOTH h buffers; stage x (4 seqs) -> LDS fp16 ----
    for (int i = tid; i < 10752 / 4; i += 512)
        ((unsigned*)(pool_ + OFF_HA))[i] = 0;          // hA + hB (contiguous)
    for (int idx = tid; idx < NB_ * T_ * F_; idx += 512) {   // 4096
        int s = idx >> 10, rem = idx & 1023;                 // rem = t*16+f
        xh[s * XSTR + rem] = f2h(x[(size_t)(nb + s) * 1024 + rem]);
    }

    // ---- A-frags Whh fp16: row ra = 128g + 16wv + lN; k = ks*32 + lK*8 + i
    s16x8 wf[4][4];
    #pragma unroll
    for (int g = 0; g < 4; ++g) {
        const int ra = 128 * g + 16 * wv + lN;
        #pragma unroll
        for (int ks = 0; ks < 4; ++ks) {
            const float4* p = (const float4*)(W_hh + (size_t)ra * 128 + ks * 32 + lK * 8);
            float4 v0 = p[0], v1 = p[1];
            float w[8] = {v0.x,v0.y,v0.z,v0.w, v1.x,v1.y,v1.z,v1.w};
            #pragma unroll
            for (int i = 0; i < 8; ++i) wf[g][ks][i] = (short)f2h(w[i]);
        }
    }
    // Wih fp16 frags: K=16 padded to 32; lanes lK>=2 get zero A.
    s16x8 wif[4];
    #pragma unroll
    for (int g = 0; g < 4; ++g) {
        const int ra = 128 * g + 16 * wv + lN;
        const float4* p = (const float4*)(W_ih + (size_t)ra * 16 + (lK & 1) * 8);
        float4 v0 = p[0], v1 = p[1];
        float w[8] = {v0.x,v0.y,v0.z,v0.w, v1.x,v1.y,v1.z,v1.w};
        #pragma unroll
        for (int i = 0; i < 8; ++i)
            wif[g][i] = (short)((lK < 2) ? f2h(w[i]) : 0);
    }
    // bias folded into acc init: rows 128g + 16wv + 4lK + r
    f32x4 bias4[4];
    #pragma unroll
    for (int g = 0; g < 4; ++g)
        #pragma unroll
        for (int r = 0; r < 4; ++r) {
            int rr = 128 * g + 16 * wv + 4 * lK + r;
            bias4[g][r] = b_ih[rr] + b_hh[rr];
        }
    __syncthreads();

    // ---- recurrent loop ----
    // Gather: lane L owns cell (jloc = L>>2, sloc = L&3); src lane
    // (L&3) + 16*(L>>4), register r = (L>>2)&3. One cell update per lane.
    const int hoff = lN * HSTR;
    const ushort* xrow = xh + (lN & 3) * XSTR + (lK & 1) * 8;
    const int srcLane = (lane & 3) + 16 * (lane >> 4);
    const int rsel    = (lane >> 2) & 3;
    const int jloc    = lane >> 2;          // 0..15
    const int sloc    = lane & 3;           // 0..3
    const int hwoff   = sloc * HSTR + 16 * wv + jloc;   // h write slot (2B)
    ushort* repL = rep + ((size_t)(nb + sloc) * T_) * H_ + 16 * wv + jloc;
    float cst = 0.f;
    #pragma unroll 1
    for (int tb = 0; tb < 16; ++tb) {
        s16x8 bx0 = *(const s16x8*)(xrow + (4 * tb + 0) * 16);
        s16x8 bx1 = *(const s16x8*)(xrow + (4 * tb + 1) * 16);
        s16x8 bx2 = *(const s16x8*)(xrow + (4 * tb + 2) * 16);
        s16x8 bx3 = *(const s16x8*)(xrow + (4 * tb + 3) * 16);
        #pragma unroll
        for (int u = 0; u < 4; ++u) {
            const int t = 4 * tb + u;
            s16x8 bx = (u == 0) ? bx0 : (u == 1) ? bx1 : (u == 2) ? bx2 : bx3;

            f32x4 acc0 = MFMA16(wif[0], bx, bias4[0]);
            f32x4 acc1 = MFMA16(wif[1], bx, bias4[1]);
            f32x4 acc2 = MFMA16(wif[2], bx, bias4[2]);
            f32x4 acc3 = MFMA16(wif[3], bx, bias4[3]);

            const ushort* hh = (u & 1) ? hB : hA;     // compile-time select
            #pragma unroll
            for (int ks = 0; ks < 4; ++ks) {
                s16x8 bh = *(const s16x8*)(hh + hoff + ks * 32 + lK * 8);
                acc0 = MFMA16(wf[0][ks], bh, acc0);
                acc1 = MFMA16(wf[1][ks], bh, acc1);
                acc2 = MFMA16(wf[2][ks], bh, acc2);
                acc3 = MFMA16(wf[3][ks], bh, acc3);
            }

            // redistribute the 4 gate values for this lane's (jloc, sloc)
            float t0, t1, t2, t3, gi, gf, gg, go;
            t0 = __shfl(acc0[0], srcLane); t1 = __shfl(acc0[1], srcLane);
            t2 = __shfl(acc0[2], srcLane); t3 = __shfl(acc0[3], srcLane);
            gi = (rsel < 2) ? (rsel ? t1 : t0) : ((rsel == 2) ? t2 : t3);
            t0 = __shfl(acc1[0], srcLane); t1 = __shfl(acc1[1], srcLane);
            t2 = __shfl(acc1[2], srcLane); t3 = __shfl(acc1[3], srcLane);
            gf = (rsel < 2) ? (rsel ? t1 : t0) : ((rsel == 2) ? t2 : t3);
            t0 = __shfl(acc2[0], srcLane); t1 = __shfl(acc2[1], srcLane);
            t2 = __shfl(acc2[2], srcLane); t3 = __shfl(acc2[3], srcLane);
            gg = (rsel < 2) ? (rsel ? t1 : t0) : ((rsel == 2) ? t2 : t3);
            t0 = __shfl(acc3[0], srcLane); t1 = __shfl(acc3[1], srcLane);
            t2 = __shfl(acc3[2], srcLane); t3 = __shfl(acc3[3], srcLane);
            go = (rsel < 2) ? (rsel ? t1 : t0) : ((rsel == 2) ? t2 : t3);

            // ONE cell update per lane
            float ii = sigmoidf_(gi);
            float ff = sigmoidf_(gf);
            float gt = tanhf_(gg);
            float oo = sigmoidf_(go);
            float c  = ff * cst + ii * gt;
            cst = c;
            ushort hb = f2h(oo * tanhf_(c));

            ushort* hw = (u & 1) ? hA : hB;           // write the OTHER buffer
            hw[hwoff] = hb;                           // 2B LDS write
            repL[(size_t)t * H_] = hb;                // 2B global (floats to L2)
            BAR_LDS();                                // LDS-only barrier
        }
    }

    // ================= epilogue (4 seqs in this block) =================
    // E0: stage w1 (fp16, stride 140) + wa/ba  (recurrence LDS dead)
    for (int idx = tid; idx < 128 * 128; idx += 512) {
        int o = idx >> 7, k = idx & 127;
        w1h[o * 140 + k] = f2h(w1[idx]);
    }
    if (tid < 128) wab[tid] = wa[tid];
    if (tid == 128) wab[128] = ba[0];
    __syncthreads();   // FULL barrier: drains vmcnt(0) -> rep stores visible

    // E1: a2[s][o] = h63 @ w2^T + b1 + b2  (wave 0; A rows >=4 dup of row&3)
    if (wv == 0) {
        s16x8 ar[4];
        #pragma unroll
        for (int ks = 0; ks < 4; ++ks)
            ar[ks] = *(const s16x8*)(rep + ((size_t)(nb + (lN & 3)) * T_ + 63) * H_ + ks * 32 + lK * 8);
        #pragma unroll
        for (int nt = 0; nt < 8; ++nt) {
            f32x4 acc = {0.f,0.f,0.f,0.f};
            const int o = 16 * nt + lN;
            #pragma unroll
            for (int ks = 0; ks < 4; ++ks) {
                const float4* p = (const float4*)(w2 + (size_t)o * 128 + ks * 32 + lK * 8);
                float4 v0 = p[0], v1 = p[1];
                s16x8 bb;
                bb[0]=(short)f2h(v0.x); bb[1]=(short)f2h(v0.y); bb[2]=(short)f2h(v0.z); bb[3]=(short)f2h(v0.w);
                bb[4]=(short)f2h(v1.x); bb[5]=(short)f2h(v1.y); bb[6]=(short)f2h(v1.z); bb[7]=(short)f2h(v1.w);
                acc = MFMA16(ar[ks], bb, acc);
            }
            float bb12 = b1[o] + b2[o];
            #pragma unroll
            for (int r = 0; r < 4; ++r)
                a2s[(4 * lK + r) * 128 + o] = acc[r] + bb12;   // seq = 4lK+r
        }
    }
    __syncthreads();

    // E2: logits[t] = sum_o wa[o]*tanh((rep @ w1^T)[t][o] + a2[o])
    // 2 waves per seq: seq = wv>>1, mt = (wv&1)*2 + mtl
    {
        const int seq = wv >> 1;
        #pragma unroll 1
        for (int mtl = 0; mtl < 2; ++mtl) {
            const int mt = (wv & 1) * 2 + mtl;
            s16x8 ar[4];
            #pragma unroll
            for (int ks = 0; ks < 4; ++ks)
                ar[ks] = *(const s16x8*)(rep + ((size_t)(nb + seq) * T_ + 16 * mt + lN) * H_ + ks * 32 + lK * 8);
            float part[4] = {0.f,0.f,0.f,0.f};
            #pragma unroll
            for (int nt = 0; nt < 8; ++nt) {
                f32x4 acc = {0.f,0.f,0.f,0.f};
                #pragma unroll
                for (int ks = 0; ks < 4; ++ks)
                    acc = MFMA16(ar[ks],
                                 *(const s16x8*)(w1h + (lN + 16 * nt) * 140 + ks * 32 + lK * 8),
                                 acc);
                const int o = lN + 16 * nt;
                const float wao = wab[o];
                const float a2o = a2s[seq * 128 + o];
                #pragma unroll
                for (int r = 0; r < 4; ++r)
                    part[r] += wao * tanhf_(acc[r] + a2o);
            }
            #pragma unroll
            for (int r = 0; r < 4; ++r) {
                part[r] += __shfl_xor(part[r], 1);
                part[r] += __shfl_xor(part[r], 2);
                part[r] += __shfl_xor(part[r], 4);
                part[r] += __shfl_xor(part[r], 8);
            }
            if (lN == 0) {
                float4 st; st.x = part[0]; st.y = part[1]; st.z = part[2]; st.w = part[3];
                *(float4*)(logitb + seq * 64 + 16 * mt + 4 * lK) = st;  // t = 16mt+4lK+r
            }
        }
    }
    __syncthreads();

    // E3: softmax over 64 logits, seq = wv (waves 0..3)
    if (wv < NB_) {
        const int seq = wv;
        float vl = logitb[seq * 64 + lane] + wab[128];
        float m = vl;
        #pragma unroll
        for (int off = 1; off < 64; off <<= 1) m = fmaxf(m, __shfl_xor(m, off));
        float e = __expf(vl - m);
        float ss = e;
        #pragma unroll
        for (int off = 1; off < 64; off <<= 1) ss += __shfl_xor(ss, off);
        alph[seq * 64 + lane] = e / ss;
    }
    __syncthreads();

    // E4: stock_rep[s][h] = sum_t alpha * rep  (fp32, into a2s alias)
    {
        const int s = tid >> 7, o = tid & 127;     // 1 element per thread
        float acc = 0.f;
        const ushort* rp = rep + (size_t)(nb + s) * T_ * H_ + o;
        #pragma unroll 8
        for (int t = 0; t < T_; ++t)
            acc += alph[s * 64 + t] * h2f(rp[(size_t)t * H_]);
        __syncthreads();                           // a2s readers (E2) done
        a2s[s * 128 + o] = acc;
    }
    __syncthreads();

    // E5: q,k,v = sr @ W^T + b  (fp32 VALU; one seq per thread-group)
    {
        const float* sr = a2s;
        const int o = tid & 127, sg = tid >> 7;    // sg = seq 0..3
        float aq = 0.f, ak = 0.f, av = 0.f;
        for (int k = 0; k < 128; k += 4) {
            float4 q4 = *(const float4*)(wq  + (size_t)o * 128 + k);
            float4 k4 = *(const float4*)(wk  + (size_t)o * 128 + k);
            float4 v4 = *(const float4*)(wvm + (size_t)o * 128 + k);
            float4 s4 = *(const float4*)(sr + sg * 128 + k);
            aq += q4.x*s4.x + q4.y*s4.y + q4.z*s4.z + q4.w*s4.w;
            ak += k4.x*s4.x + k4.y*s4.y + k4.z*s4.z + k4.w*s4.w;
            av += v4.x*s4.x + v4.y*s4.y + v4.z*s4.z + v4.w*s4.w;
        }
        qout[(size_t)(nb + sg) * H_ + o] = aq + bq[o];
        kout[(size_t)(nb + sg) * H_ + o] = ak + bk[o];
        vout[(size_t)(nb + sg) * H_ + o] = av + bv[o];
    }
}

// Cross-asset attention: one block per (b, m) query row, 256 threads. fp32 out.
__global__ __launch_bounds__(256, 4)
void caan(const float* __restrict__ qb, const float* __restrict__ kb,
          const float* __restrict__ vb, const float* __restrict__ ww,
          const float* __restrict__ bw, float* __restrict__ out)
{
    __shared__ alignas(16) float qs[H_];
    __shared__ alignas(16) float sc[512];
    __shared__ alignas(16) float red[8];
    __shared__ alignas(16) float pv[2][H_];

    const int n   = blockIdx.x;
    const int b   = n >> 9;
    const int tid = threadIdx.x;

    if (tid < H_) qs[tid] = qb[n * H_ + tid];
    __syncthreads();

    const float scale = 0.08838834764831845f;  // 1/sqrt(128)
    float s0raw = 0.f, s1raw = 0.f;
    #pragma unroll
    for (int r = 0; r < 2; ++r) {
        const int j = tid + r * 256;
        const float4* kp = (const float4*)(kb + (size_t)(b * 512 + j) * H_);
        const float4* qp = (const float4*)qs;
        float c0=0.f,c1=0.f,c2=0.f,c3=0.f;
        #pragma unroll
        for (int i = 0; i < 32; ++i) {
            float4 kv = kp[i], qv = qp[i];
            c0 += kv.x*qv.x; c1 += kv.y*qv.y; c2 += kv.z*qv.z; c3 += kv.w*qv.w;
        }
        float sres = ((c0 + c1) + (c2 + c3)) * scale;
        if (r == 0) s0raw = sres; else s1raw = sres;
    }

    float m = fmaxf(s0raw, s1raw);
    #pragma unroll
    for (int off = 1; off < 64; off <<= 1) m = fmaxf(m, __shfl_xor(m, off));
    if ((tid & 63) == 0) red[tid >> 6] = m;
    __syncthreads();
    m = fmaxf(fmaxf(red[0], red[1]), fmaxf(red[2], red[3]));
    float e0 = __expf(s0raw - m), e1 = __expf(s1raw - m);
    sc[tid] = e0; sc[tid + 256] = e1;
    float lsum = e0 + e1;
    #pragma unroll
    for (int off = 1; off < 64; off <<= 1) lsum += __shfl_xor(lsum, off);
    if ((tid & 63) == 0) red[4 + (tid >> 6)] = lsum;
    __syncthreads();
    const float inv = 1.0f / ((red[4] + red[5]) + (red[6] + red[7]));

    const int o  = tid & (H_ - 1);
    const int jh = tid >> 7;
    const float* vp = vb + (size_t)(b * 512 + jh * 256) * H_ + o;
    float a0=0.f,a1=0.f,a2=0.f,a3=0.f;
    for (int j = 0; j < 256; j += 4) {
        a0 += sc[jh*256 + j + 0] * vp[(size_t)(j + 0) * H_];
        a1 += sc[jh*256 + j + 1] * vp[(size_t)(j + 1) * H_];
        a2 += sc[jh*256 + j + 2] * vp[(size_t)(j + 2) * H_];
        a3 += sc[jh*256 + j + 3] * vp[(size_t)(j + 3) * H_];
    }
    pv[jh][o] = (a0 + a1) + (a2 + a3);
    __syncthreads();
    if (tid < H_) {
        float s = (pv[0][tid] + pv[1][tid]) * inv * ww[tid];
        s += __shfl_xor(s, 1);  s += __shfl_xor(s, 2);  s += __shfl_xor(s, 4);
        s += __shfl_xor(s, 8);  s += __shfl_xor(s, 16); s += __shfl_xor(s, 32);
        if ((tid & 63) == 0) red[tid >> 6] = s;
    }
    __syncthreads();
    if (tid == 0) out[n] = red[0] + red[1] + bw[0];
}

extern "C" void kernel_launch(void* const* d_in, const int* in_sizes, int n_in,
                              void* d_out, int out_size, void* d_ws, size_t ws_size,
                              hipStream_t stream)
{
    const float* x    = (const float*)d_in[0];
    const float* W_ih = (const float*)d_in[1];
    const float* W_hh = (const float*)d_in[2];
    const float* b_ih = (const float*)d_in[3];
    const float* b_hh = (const float*)d_in[4];
    const float* w1   = (const float*)d_in[5];
    const float* b1   = (const float*)d_in[6];
    const float* w2   = (const float*)d_in[7];
    const float* b2   = (const float*)d_in[8];
    const float* wa   = (const float*)d_in[9];
    const float* ba   = (const float*)d_in[10];
    const float* wq   = (const float*)d_in[11];
    const float* bq   = (const float*)d_in[12];
    const float* wk   = (const float*)d_in[13];
    const float* bk   = (const float*)d_in[14];
    const float* wv   = (const float*)d_in[15];
    const float* bv   = (const float*)d_in[16];
    const float* ww   = (const float*)d_in[17];
    const float* bw   = (const float*)d_in[18];

    float* ws   = (float*)d_ws;
    float* qbuf = ws;                              // 1024*128 f32
    float* kbuf = ws + (size_t)NSEQ_ * H_;
    float* vbuf = ws + (size_t)2 * NSEQ_ * H_;
    ushort* rep = (ushort*)(ws + (size_t)3 * NSEQ_ * H_);        // 16 MB fp16

    alphastock_main<<<NBLK_, 512, 0, stream>>>(x, W_ih, W_hh, b_ih, b_hh,
                                               w1, b1, w2, b2, wa, ba,
                                               wq, bq, wk, bk, wv, bv,
                                               rep, qbuf, kbuf, vbuf);
    caan<<<NSEQ_, 256, 0, stream>>>(qbuf, kbuf, vbuf, ww, bw, (float*)d_out);
}

// Round 16
// 166.312 us; speedup vs baseline: 1.3292x; 1.0447x over previous
//
#include <hip/hip_runtime.h>
#include <hip/hip_bf16.h>

#define DEVI __device__ __forceinline__

typedef float f32x4 __attribute__((ext_vector_type(4)));
typedef short s16x8 __attribute__((ext_vector_type(8)));

constexpr int T_ = 64;    // window
constexpr int F_ = 16;    // features
constexpr int H_ = 128;   // hidden
constexpr int NSEQ_ = 1024;
constexpr int NB_ = 4;    // sequences per block (MFMA N cols 4..15 don't-care)
constexpr int NBLK_ = NSEQ_ / NB_;  // 256 blocks -> every CU gets work

DEVI float sigmoidf_(float x) { return 1.0f / (1.0f + __expf(-x)); }
DEVI float tanhf_(float x) {
    float a = fabsf(x);
    float e = __expf(-2.0f * a);
    return copysignf((1.0f - e) / (1.0f + e), x);
}
DEVI ushort f2h(float f) {              // fp32 -> fp16 bits
    _Float16 h = (_Float16)f;
    ushort b; __builtin_memcpy(&b, &h, 2); return b;
}
DEVI float h2f(ushort b) {
    _Float16 h; __builtin_memcpy(&h, &b, 2); return (float)h;
}
DEVI unsigned pkh(float a, float b) {   // v_cvt_pkrtz_f16_f32: (a,b)->u32
    auto v = __builtin_amdgcn_cvt_pkrtz(a, b);   // __fp16 ext_vector(2)
    unsigned u; __builtin_memcpy(&u, &v, 4); return u;
}
DEVI float lo16(unsigned u) { ushort s = (ushort)(u & 0xffff);  return h2f(s); }
DEVI float hi16(unsigned u) { ushort s = (ushort)(u >> 16);     return h2f(s); }

#define MFMA16(A,B,C) __builtin_amdgcn_mfma_f32_16x16x32_f16((A),(B),(C),0,0,0)

// In-loop barrier: order LDS ops only (lgkmcnt); rep global stores float
// across steps and are drained by the epilogue's full __syncthreads().
#define BAR_LDS() asm volatile("s_waitcnt lgkmcnt(0)\n\ts_barrier" ::: "memory")

// LDS pool, phase-aliased (52768 B):
//  recurrence: xh ushort[4][1032] @0 (8256B)  [x fp16, 4 real seqs]
//              hA @8320 (5376B), hB @13696 (5376B)   [h fp16 ping-pong, 16 rows]
//  epilogue (recurrence regions dead):
//              w1h ushort[128][140] @0 (35840B)
//              a2s  float[16][128]  @35840
//              logitb float[16][64] @44032
//              alph   float[16][64] @48128
//              wab    float[132]    @52224
constexpr int XSTR = 1032;
constexpr int HSTR = 168;   // f16 per h row (336 B)
constexpr int OFF_HA  = 8320, OFF_HB = 13696;
constexpr int OFF_A2S = 35840, OFF_LOG = 44032, OFF_ALPH = 48128, OFF_WAB = 52224;
constexpr int POOL_BYTES = 52768;

__global__ __launch_bounds__(512, 2)
void alphastock_main(const float* __restrict__ x,
                     const float* __restrict__ W_ih, const float* __restrict__ W_hh,
                     const float* __restrict__ b_ih, const float* __restrict__ b_hh,
                     const float* __restrict__ w1, const float* __restrict__ b1,
                     const float* __restrict__ w2, const float* __restrict__ b2,
                     const float* __restrict__ wa, const float* __restrict__ ba,
                     const float* __restrict__ wq, const float* __restrict__ bq,
                     const float* __restrict__ wk, const float* __restrict__ bk,
                     const float* __restrict__ wvm, const float* __restrict__ bv,
                     ushort* __restrict__ rep,   // [1024][64][128] fp16 ws
                     float* __restrict__ qout, float* __restrict__ kout,
                     float* __restrict__ vout)
{
    __shared__ alignas(16) char pool_[POOL_BYTES];
    ushort* xh    = (ushort*)pool_;
    ushort* hA    = (ushort*)(pool_ + OFF_HA);
    ushort* hB    = (ushort*)(pool_ + OFF_HB);
    ushort* w1h   = (ushort*)pool_;                    // epilogue alias
    float*  a2s   = (float*)(pool_ + OFF_A2S);
    float*  logitb= (float*)(pool_ + OFF_LOG);
    float*  alph  = (float*)(pool_ + OFF_ALPH);
    float*  wab   = (float*)(pool_ + OFF_WAB);

    const int tid  = threadIdx.x;
    const int wv   = tid >> 6;        // wave 0..7
    const int lane = tid & 63;
    const int lN   = lane & 15;       // frag col (seq; real 0..3) / A-row
    const int lK   = lane >> 4;       // k-group 0..3
    const int nb   = blockIdx.x * NB_;

    // ---- prologue: zero BOTH h buffers; stage x (4 seqs) -> LDS fp16 ----
    for (int i = tid; i < 10752 / 4; i += 512)
        ((unsigned*)(pool_ + OFF_HA))[i] = 0;          // hA + hB (contiguous)
    for (int idx = tid; idx < NB_ * T_ * F_; idx += 512) {   // 4096
        int s = idx >> 10, rem = idx & 1023;                 // rem = t*16+f
        xh[s * XSTR + rem] = f2h(x[(size_t)(nb + s) * 1024 + rem]);
    }

    // ---- A-frags Whh fp16: row ra = 128g + 16wv + lN; k = ks*32 + lK*8 + i
    s16x8 wf[4][4];
    #pragma unroll
    for (int g = 0; g < 4; ++g) {
        const int ra = 128 * g + 16 * wv + lN;
        #pragma unroll
        for (int ks = 0; ks < 4; ++ks) {
            const float4* p = (const float4*)(W_hh + (size_t)ra * 128 + ks * 32 + lK * 8);
            float4 v0 = p[0], v1 = p[1];
            float w[8] = {v0.x,v0.y,v0.z,v0.w, v1.x,v1.y,v1.z,v1.w};
            #pragma unroll
            for (int i = 0; i < 8; ++i) wf[g][ks][i] = (short)f2h(w[i]);
        }
    }
    // Wih fp16 frags: K=16 padded to 32; lanes lK>=2 get zero A.
    s16x8 wif[4];
    #pragma unroll
    for (int g = 0; g < 4; ++g) {
        const int ra = 128 * g + 16 * wv + lN;
        const float4* p = (const float4*)(W_ih + (size_t)ra * 16 + (lK & 1) * 8);
        float4 v0 = p[0], v1 = p[1];
        float w[8] = {v0.x,v0.y,v0.z,v0.w, v1.x,v1.y,v1.z,v1.w};
        #pragma unroll
        for (int i = 0; i < 8; ++i)
            wif[g][i] = (short)((lK < 2) ? f2h(w[i]) : 0);
    }
    // bias folded into acc init: rows 128g + 16wv + 4lK + r
    f32x4 bias4[4];
    #pragma unroll
    for (int g = 0; g < 4; ++g)
        #pragma unroll
        for (int r = 0; r < 4; ++r) {
            int rr = 128 * g + 16 * wv + 4 * lK + r;
            bias4[g][r] = b_ih[rr] + b_hh[rr];
        }
    __syncthreads();

    // ---- recurrent loop ----
    // Gather: lane L owns cell (jloc = L>>2, sloc = L&3); src lane
    // (L&3) + 16*(L>>4), register r = (L>>2)&3. Gate preacts packed as
    // fp16 pairs -> 8 bpermute/step instead of 16 (DS pipe is the
    // block-shared bottleneck: 8 waves x DS ops serialize on one LDS unit).
    const int hoff = lN * HSTR;
    const ushort* xrow = xh + (lN & 3) * XSTR + (lK & 1) * 8;
    const int srcLane = (lane & 3) + 16 * (lane >> 4);
    const int rsel    = (lane >> 2) & 3;
    const int jloc    = lane >> 2;          // 0..15
    const int sloc    = lane & 3;           // 0..3
    const int hwoff   = sloc * HSTR + 16 * wv + jloc;   // h write slot (2B)
    ushort* repL = rep + ((size_t)(nb + sloc) * T_) * H_ + 16 * wv + jloc;
    const f32x4 zc = {0.f, 0.f, 0.f, 0.f};
    float cst = 0.f;
    #pragma unroll 1
    for (int tb = 0; tb < 16; ++tb) {
        s16x8 bx0 = *(const s16x8*)(xrow + (4 * tb + 0) * 16);
        s16x8 bx1 = *(const s16x8*)(xrow + (4 * tb + 1) * 16);
        s16x8 bx2 = *(const s16x8*)(xrow + (4 * tb + 2) * 16);
        s16x8 bx3 = *(const s16x8*)(xrow + (4 * tb + 3) * 16);
        #pragma unroll
        for (int u = 0; u < 4; ++u) {
            const int t = 4 * tb + u;
            s16x8 bx = (u == 0) ? bx0 : (u == 1) ? bx1 : (u == 2) ? bx2 : bx3;

            const ushort* hh = (u & 1) ? hB : hA;     // compile-time select
            s16x8 bh0 = *(const s16x8*)(hh + hoff + 0 * 32 + lK * 8);
            s16x8 bh1 = *(const s16x8*)(hh + hoff + 1 * 32 + lK * 8);
            s16x8 bh2 = *(const s16x8*)(hh + hoff + 2 * 32 + lK * 8);
            s16x8 bh3 = *(const s16x8*)(hh + hoff + 3 * 32 + lK * 8);

            // two parallel chains per gate: (wif->ks0->ks1) || (ks2->ks3)
            f32x4 a0 = MFMA16(wif[0], bx, bias4[0]);
            f32x4 a1 = MFMA16(wif[1], bx, bias4[1]);
            f32x4 a2 = MFMA16(wif[2], bx, bias4[2]);
            f32x4 a3 = MFMA16(wif[3], bx, bias4[3]);
            a0 = MFMA16(wf[0][0], bh0, a0); a1 = MFMA16(wf[1][0], bh0, a1);
            a2 = MFMA16(wf[2][0], bh0, a2); a3 = MFMA16(wf[3][0], bh0, a3);
            a0 = MFMA16(wf[0][1], bh1, a0); a1 = MFMA16(wf[1][1], bh1, a1);
            a2 = MFMA16(wf[2][1], bh1, a2); a3 = MFMA16(wf[3][1], bh1, a3);
            f32x4 d0 = MFMA16(wf[0][2], bh2, zc);
            f32x4 d1 = MFMA16(wf[1][2], bh2, zc);
            f32x4 d2 = MFMA16(wf[2][2], bh2, zc);
            f32x4 d3 = MFMA16(wf[3][2], bh2, zc);
            d0 = MFMA16(wf[0][3], bh3, d0); d1 = MFMA16(wf[1][3], bh3, d1);
            d2 = MFMA16(wf[2][3], bh3, d2); d3 = MFMA16(wf[3][3], bh3, d3);

            // pack per-r gate pairs (chain-merge add folded into pack input)
            unsigned wA0 = pkh(a0[0] + d0[0], a1[0] + d1[0]);
            unsigned wA1 = pkh(a0[1] + d0[1], a1[1] + d1[1]);
            unsigned wA2 = pkh(a0[2] + d0[2], a1[2] + d1[2]);
            unsigned wA3 = pkh(a0[3] + d0[3], a1[3] + d1[3]);
            unsigned wB0 = pkh(a2[0] + d2[0], a3[0] + d3[0]);
            unsigned wB1 = pkh(a2[1] + d2[1], a3[1] + d3[1]);
            unsigned wB2 = pkh(a2[2] + d2[2], a3[2] + d3[2]);
            unsigned wB3 = pkh(a2[3] + d2[3], a3[3] + d3[3]);

            // 8 bpermutes + rsel select
            unsigned A0 = (unsigned)__shfl((int)wA0, srcLane);
            unsigned A1 = (unsigned)__shfl((int)wA1, srcLane);
            unsigned A2 = (unsigned)__shfl((int)wA2, srcLane);
            unsigned A3 = (unsigned)__shfl((int)wA3, srcLane);
            unsigned B0 = (unsigned)__shfl((int)wB0, srcLane);
            unsigned B1 = (unsigned)__shfl((int)wB1, srcLane);
            unsigned B2 = (unsigned)__shfl((int)wB2, srcLane);
            unsigned B3 = (unsigned)__shfl((int)wB3, srcLane);
            unsigned gA = (rsel < 2) ? (rsel ? A1 : A0) : ((rsel == 2) ? A2 : A3);
            unsigned gB = (rsel < 2) ? (rsel ? B1 : B0) : ((rsel == 2) ? B2 : B3);

            // ONE cell update per lane (gate preacts fp16: ~2^-11, same
            // precision class as the fp16 h that already passes)
            float ii = sigmoidf_(lo16(gA));
            float ff = sigmoidf_(hi16(gA));
            float gt = tanhf_  (lo16(gB));
            float oo = sigmoidf_(hi16(gB));
            float c  = ff * cst + ii * gt;
            cst = c;
            ushort hb = f2h(oo * tanhf_(c));

            ushort* hw = (u & 1) ? hA : hB;           // write the OTHER buffer
            hw[hwoff] = hb;                           // 2B LDS write
            repL[(size_t)t * H_] = hb;                // 2B global (floats to L2)
            BAR_LDS();                                // LDS-only barrier
        }
    }

    // ================= epilogue (4 seqs in this block) =================
    // E0: stage w1 (fp16, stride 140) + wa/ba  (recurrence LDS dead)
    for (int idx = tid; idx < 128 * 128; idx += 512) {
        int o = idx >> 7, k = idx & 127;
        w1h[o * 140 + k] = f2h(w1[idx]);
    }
    if (tid < 128) wab[tid] = wa[tid];
    if (tid == 128) wab[128] = ba[0];
    __syncthreads();   // FULL barrier: drains vmcnt(0) -> rep stores visible

    // E1: a2[s][o] = h63 @ w2^T + b1 + b2  (wave 0; A rows >=4 dup of row&3)
    if (wv == 0) {
        s16x8 ar[4];
        #pragma unroll
        for (int ks = 0; ks < 4; ++ks)
            ar[ks] = *(const s16x8*)(rep + ((size_t)(nb + (lN & 3)) * T_ + 63) * H_ + ks * 32 + lK * 8);
        #pragma unroll
        for (int nt = 0; nt < 8; ++nt) {
            f32x4 acc = {0.f,0.f,0.f,0.f};
            const int o = 16 * nt + lN;
            #pragma unroll
            for (int ks = 0; ks < 4; ++ks) {
                const float4* p = (const float4*)(w2 + (size_t)o * 128 + ks * 32 + lK * 8);
                float4 v0 = p[0], v1 = p[1];
                s16x8 bb;
                bb[0]=(short)f2h(v0.x); bb[1]=(short)f2h(v0.y); bb[2]=(short)f2h(v0.z); bb[3]=(short)f2h(v0.w);
                bb[4]=(short)f2h(v1.x); bb[5]=(short)f2h(v1.y); bb[6]=(short)f2h(v1.z); bb[7]=(short)f2h(v1.w);
                acc = MFMA16(ar[ks], bb, acc);
            }
            float bb12 = b1[o] + b2[o];
            #pragma unroll
            for (int r = 0; r < 4; ++r)
                a2s[(4 * lK + r) * 128 + o] = acc[r] + bb12;   // seq = 4lK+r
        }
    }
    __syncthreads();

    // E2: logits[t] = sum_o wa[o]*tanh((rep @ w1^T)[t][o] + a2[o])
    // 2 waves per seq: seq = wv>>1, mt = (wv&1)*2 + mtl
    {
        const int seq = wv >> 1;
        #pragma unroll 1
        for (int mtl = 0; mtl < 2; ++mtl) {
            const int mt = (wv & 1) * 2 + mtl;
            s16x8 ar[4];
            #pragma unroll
            for (int ks = 0; ks < 4; ++ks)
                ar[ks] = *(const s16x8*)(rep + ((size_t)(nb + seq) * T_ + 16 * mt + lN) * H_ + ks * 32 + lK * 8);
            float part[4] = {0.f,0.f,0.f,0.f};
            #pragma unroll
            for (int nt = 0; nt < 8; ++nt) {
                f32x4 acc = {0.f,0.f,0.f,0.f};
                #pragma unroll
                for (int ks = 0; ks < 4; ++ks)
                    acc = MFMA16(ar[ks],
                                 *(const s16x8*)(w1h + (lN + 16 * nt) * 140 + ks * 32 + lK * 8),
                                 acc);
                const int o = lN + 16 * nt;
                const float wao = wab[o];
                const float a2o = a2s[seq * 128 + o];
                #pragma unroll
                for (int r = 0; r < 4; ++r)
                    part[r] += wao * tanhf_(acc[r] + a2o);
            }
            #pragma unroll
            for (int r = 0; r < 4; ++r) {
                part[r] += __shfl_xor(part[r], 1);
                part[r] += __shfl_xor(part[r], 2);
                part[r] += __shfl_xor(part[r], 4);
                part[r] += __shfl_xor(part[r], 8);
            }
            if (lN == 0) {
                float4 st; st.x = part[0]; st.y = part[1]; st.z = part[2]; st.w = part[3];
                *(float4*)(logitb + seq * 64 + 16 * mt + 4 * lK) = st;  // t = 16mt+4lK+r
            }
        }
    }
    __syncthreads();

    // E3: softmax over 64 logits, seq = wv (waves 0..3)
    if (wv < NB_) {
        const int seq = wv;
        float vl = logitb[seq * 64 + lane] + wab[128];
        float m = vl;
        #pragma unroll
        for (int off = 1; off < 64; off <<= 1) m = fmaxf(m, __shfl_xor(m, off));
        float e = __expf(vl - m);
        float ss = e;
        #pragma unroll
        for (int off = 1; off < 64; off <<= 1) ss += __shfl_xor(ss, off);
        alph[seq * 64 + lane] = e / ss;
    }
    __syncthreads();

    // E4: stock_rep[s][h] = sum_t alpha * rep  (fp32, into a2s alias)
    {
        const int s = tid >> 7, o = tid & 127;     // 1 element per thread
        float acc = 0.f;
        const ushort* rp = rep + (size_t)(nb + s) * T_ * H_ + o;
        #pragma unroll 8
        for (int t = 0; t < T_; ++t)
            acc += alph[s * 64 + t] * h2f(rp[(size_t)t * H_]);
        __syncthreads();                           // a2s readers (E2) done
        a2s[s * 128 + o] = acc;
    }
    __syncthreads();

    // E5: q,k,v = sr @ W^T + b  (fp32 VALU; one seq per thread-group)
    {
        const float* sr = a2s;
        const int o = tid & 127, sg = tid >> 7;    // sg = seq 0..3
        float aq = 0.f, ak = 0.f, av = 0.f;
        for (int k = 0; k < 128; k += 4) {
            float4 q4 = *(const float4*)(wq  + (size_t)o * 128 + k);
            float4 k4 = *(const float4*)(wk  + (size_t)o * 128 + k);
            float4 v4 = *(const float4*)(wvm + (size_t)o * 128 + k);
            float4 s4 = *(const float4*)(sr + sg * 128 + k);
            aq += q4.x*s4.x + q4.y*s4.y + q4.z*s4.z + q4.w*s4.w;
            ak += k4.x*s4.x + k4.y*s4.y + k4.z*s4.z + k4.w*s4.w;
            av += v4.x*s4.x + v4.y*s4.y + v4.z*s4.z + v4.w*s4.w;
        }
        qout[(size_t)(nb + sg) * H_ + o] = aq + bq[o];
        kout[(size_t)(nb + sg) * H_ + o] = ak + bk[o];
        vout[(size_t)(nb + sg) * H_ + o] = av + bv[o];
    }
}

// Cross-asset attention: one block per (b, m) query row, 256 threads. fp32 out.
__global__ __launch_bounds__(256, 4)
void caan(const float* __restrict__ qb, const float* __restrict__ kb,
          const float* __restrict__ vb, const float* __restrict__ ww,
          const float* __restrict__ bw, float* __restrict__ out)
{
    __shared__ alignas(16) float qs[H_];
    __shared__ alignas(16) float sc[512];
    __shared__ alignas(16) float red[8];
    __shared__ alignas(16) float pv[2][H_];

    const int n   = blockIdx.x;
    const int b   = n >> 9;
    const int tid = threadIdx.x;

    if (tid < H_) qs[tid] = qb[n * H_ + tid];
    __syncthreads();

    const float scale = 0.08838834764831845f;  // 1/sqrt(128)
    float s0raw = 0.f, s1raw = 0.f;
    #pragma unroll
    for (int r = 0; r < 2; ++r) {
        const int j = tid + r * 256;
        const float4* kp = (const float4*)(kb + (size_t)(b * 512 + j) * H_);
        const float4* qp = (const float4*)qs;
        float c0=0.f,c1=0.f,c2=0.f,c3=0.f;
        #pragma unroll
        for (int i = 0; i < 32; ++i) {
            float4 kv = kp[i], qv = qp[i];
            c0 += kv.x*qv.x; c1 += kv.y*qv.y; c2 += kv.z*qv.z; c3 += kv.w*qv.w;
        }
        float sres = ((c0 + c1) + (c2 + c3)) * scale;
        if (r == 0) s0raw = sres; else s1raw = sres;
    }

    float m = fmaxf(s0raw, s1raw);
    #pragma unroll
    for (int off = 1; off < 64; off <<= 1) m = fmaxf(m, __shfl_xor(m, off));
    if ((tid & 63) == 0) red[tid >> 6] = m;
    __syncthreads();
    m = fmaxf(fmaxf(red[0], red[1]), fmaxf(red[2], red[3]));
    float e0 = __expf(s0raw - m), e1 = __expf(s1raw - m);
    sc[tid] = e0; sc[tid + 256] = e1;
    float lsum = e0 + e1;
    #pragma unroll
    for (int off = 1; off < 64; off <<= 1) lsum += __shfl_xor(lsum, off);
    if ((tid & 63) == 0) red[4 + (tid >> 6)] = lsum;
    __syncthreads();
    const float inv = 1.0f / ((red[4] + red[5]) + (red[6] + red[7]));

    const int o  = tid & (H_ - 1);
    const int jh = tid >> 7;
    const float* vp = vb + (size_t)(b * 512 + jh * 256) * H_ + o;
    float a0=0.f,a1=0.f,a2=0.f,a3=0.f;
    for (int j = 0; j < 256; j += 4) {
        a0 += sc[jh*256 + j + 0] * vp[(size_t)(j + 0) * H_];
        a1 += sc[jh*256 + j + 1] * vp[(size_t)(j + 1) * H_];
        a2 += sc[jh*256 + j + 2] * vp[(size_t)(j + 2) * H_];
        a3 += sc[jh*256 + j + 3] * vp[(size_t)(j + 3) * H_];
    }
    pv[jh][o] = (a0 + a1) + (a2 + a3);
    __syncthreads();
    if (tid < H_) {
        float s = (pv[0][tid] + pv[1][tid]) * inv * ww[tid];
        s += __shfl_xor(s, 1);  s += __shfl_xor(s, 2);  s += __shfl_xor(s, 4);
        s += __shfl_xor(s, 8);  s += __shfl_xor(s, 16); s += __shfl_xor(s, 32);
        if ((tid & 63) == 0) red[tid >> 6] = s;
    }
    __syncthreads();
    if (tid == 0) out[n] = red[0] + red[1] + bw[0];
}

extern "C" void kernel_launch(void* const* d_in, const int* in_sizes, int n_in,
                              void* d_out, int out_size, void* d_ws, size_t ws_size,
                              hipStream_t stream)
{
    const float* x    = (const float*)d_in[0];
    const float* W_ih = (const float*)d_in[1];
    const float* W_hh = (const float*)d_in[2];
    const float* b_ih = (const float*)d_in[3];
    const float* b_hh = (const float*)d_in[4];
    const float* w1   = (const float*)d_in[5];
    const float* b1   = (const float*)d_in[6];
    const float* w2   = (const float*)d_in[7];
    const float* b2   = (const float*)d_in[8];
    const float* wa   = (const float*)d_in[9];
    const float* ba   = (const float*)d_in[10];
    const float* wq   = (const float*)d_in[11];
    const float* bq   = (const float*)d_in[12];
    const float* wk   = (const float*)d_in[13];
    const float* bk   = (const float*)d_in[14];
    const float* wv   = (const float*)d_in[15];
    const float* bv   = (const float*)d_in[16];
    const float* ww   = (const float*)d_in[17];
    const float* bw   = (const float*)d_in[18];

    float* ws   = (float*)d_ws;
    float* qbuf = ws;                              // 1024*128 f32
    float* kbuf = ws + (size_t)NSEQ_ * H_;
    float* vbuf = ws + (size_t)2 * NSEQ_ * H_;
    ushort* rep = (ushort*)(ws + (size_t)3 * NSEQ_ * H_);        // 16 MB fp16

    alphastock_main<<<NBLK_, 512, 0, stream>>>(x, W_ih, W_hh, b_ih, b_hh,
                                               w1, b1, w2, b2, wa, ba,
                                               wq, bq, wk, bk, wv, bv,
                                               rep, qbuf, kbuf, vbuf);
    caan<<<NSEQ_, 256, 0, stream>>>(qbuf, kbuf, vbuf, ww, bw, (float*)d_out);
}

// Round 17
// 163.908 us; speedup vs baseline: 1.3486x; 1.0147x over previous
//
#include <hip/hip_runtime.h>
#include <hip/hip_bf16.h>

#define DEVI __device__ __forceinline__

typedef float f32x4 __attribute__((ext_vector_type(4)));
typedef short s16x8 __attribute__((ext_vector_type(8)));

constexpr int T_ = 64;    // window
constexpr int F_ = 16;    // features
constexpr int H_ = 128;   // hidden
constexpr int NSEQ_ = 1024;
constexpr int NB_ = 4;    // sequences per block (MFMA N cols 4..15 = dups)
constexpr int NBLK_ = NSEQ_ / NB_;  // 256 blocks -> every CU gets work

DEVI float sigmoidf_(float x) { return 1.0f / (1.0f + __expf(-x)); }
DEVI float tanhf_(float x) {
    float a = fabsf(x);
    float e = __expf(-2.0f * a);
    return copysignf((1.0f - e) / (1.0f + e), x);
}
DEVI ushort f2h(float f) {              // fp32 -> fp16 bits
    _Float16 h = (_Float16)f;
    ushort b; __builtin_memcpy(&b, &h, 2); return b;
}
DEVI float h2f(ushort b) {
    _Float16 h; __builtin_memcpy(&h, &b, 2); return (float)h;
}

#define MFMA16(A,B,C) __builtin_amdgcn_mfma_f32_16x16x32_f16((A),(B),(C),0,0,0)

// In-loop barrier: order LDS ops only (lgkmcnt); rep global stores float
// across steps and are drained by the epilogue's full __syncthreads().
#define BAR_LDS() asm volatile("s_waitcnt lgkmcnt(0)\n\ts_barrier" ::: "memory")

// LDS pool, phase-aliased (52768 B):
//  recurrence: xh ushort[4][1032] @0 (8256B)  [x fp16, 4 real seqs]
//              hA @8320 (5376B), hB @13696 (5376B)   [h fp16 ping-pong, 4 rows]
//  epilogue (recurrence regions dead):
//              w1h ushort[128][140] @0 (35840B)
//              a2s  float[16][128]  @35840
//              logitb float[16][64] @44032
//              alph   float[16][64] @48128
//              wab    float[132]    @52224
constexpr int XSTR = 1032;
constexpr int HSTR = 168;   // f16 per h row (336 B)
constexpr int OFF_HA  = 8320, OFF_HB = 13696;
constexpr int OFF_A2S = 35840, OFF_LOG = 44032, OFF_ALPH = 48128, OFF_WAB = 52224;
constexpr int POOL_BYTES = 52768;

__global__ __launch_bounds__(512, 2)
void alphastock_main(const float* __restrict__ x,
                     const float* __restrict__ W_ih, const float* __restrict__ W_hh,
                     const float* __restrict__ b_ih, const float* __restrict__ b_hh,
                     const float* __restrict__ w1, const float* __restrict__ b1,
                     const float* __restrict__ w2, const float* __restrict__ b2,
                     const float* __restrict__ wa, const float* __restrict__ ba,
                     const float* __restrict__ wq, const float* __restrict__ bq,
                     const float* __restrict__ wk, const float* __restrict__ bk,
                     const float* __restrict__ wvm, const float* __restrict__ bv,
                     ushort* __restrict__ rep,   // [1024][64][128] fp16 ws
                     float* __restrict__ qout, float* __restrict__ kout,
                     float* __restrict__ vout)
{
    __shared__ alignas(16) char pool_[POOL_BYTES];
    ushort* xh    = (ushort*)pool_;
    ushort* hA    = (ushort*)(pool_ + OFF_HA);
    ushort* hB    = (ushort*)(pool_ + OFF_HB);
    ushort* w1h   = (ushort*)pool_;                    // epilogue alias
    float*  a2s   = (float*)(pool_ + OFF_A2S);
    float*  logitb= (float*)(pool_ + OFF_LOG);
    float*  alph  = (float*)(pool_ + OFF_ALPH);
    float*  wab   = (float*)(pool_ + OFF_WAB);

    const int tid  = threadIdx.x;
    const int wv   = tid >> 6;        // wave 0..7
    const int lane = tid & 63;
    const int lN   = lane & 15;       // frag col (seq dup-4) / A-row-in-tile
    const int lK   = lane >> 4;       // k-group 0..3
    const int nb   = blockIdx.x * NB_;

    // ---- prologue: zero BOTH h buffers; stage x (4 seqs) -> LDS fp16 ----
    for (int i = tid; i < 10752 / 4; i += 512)
        ((unsigned*)(pool_ + OFF_HA))[i] = 0;          // hA + hB (contiguous)
    for (int idx = tid; idx < NB_ * T_ * F_; idx += 512) {   // 4096
        int s = idx >> 10, rem = idx & 1023;                 // rem = t*16+f
        xh[s * XSTR + rem] = f2h(x[(size_t)(nb + s) * 1024 + rem]);
    }

    // ---- A-frags Whh fp16, ROW-PERMUTED so the gather disappears ----
    // Tile row lN of tile mt holds gate (lN&3) of cell c = 16wv+4mt+(lN>>2):
    // orig row = 128*(lN&3) + c. Then (C layout row=4lK+r) acc[mt][r] =
    // gate r of cell 16wv+4mt+lK, seq (lN&3) -- all 4 gates of one cell
    // live in ONE lane's registers.
    s16x8 wf[4][4];
    #pragma unroll
    for (int mt = 0; mt < 4; ++mt) {
        const int ra = 128 * (lN & 3) + 16 * wv + 4 * mt + (lN >> 2);
        #pragma unroll
        for (int ks = 0; ks < 4; ++ks) {
            const float4* p = (const float4*)(W_hh + (size_t)ra * 128 + ks * 32 + lK * 8);
            float4 v0 = p[0], v1 = p[1];
            float w[8] = {v0.x,v0.y,v0.z,v0.w, v1.x,v1.y,v1.z,v1.w};
            #pragma unroll
            for (int i = 0; i < 8; ++i) wf[mt][ks][i] = (short)f2h(w[i]);
        }
    }
    // Wih fp16 frags (same row permutation): K=16 padded to 32; lK>=2 zero.
    s16x8 wif[4];
    #pragma unroll
    for (int mt = 0; mt < 4; ++mt) {
        const int ra = 128 * (lN & 3) + 16 * wv + 4 * mt + (lN >> 2);
        const float4* p = (const float4*)(W_ih + (size_t)ra * 16 + (lK & 1) * 8);
        float4 v0 = p[0], v1 = p[1];
        float w[8] = {v0.x,v0.y,v0.z,v0.w, v1.x,v1.y,v1.z,v1.w};
        #pragma unroll
        for (int i = 0; i < 8; ++i)
            wif[mt][i] = (short)((lK < 2) ? f2h(w[i]) : 0);
    }
    // bias for acc[mt][r] = gate r of cell 16wv+4mt+lK
    f32x4 bias4[4];
    #pragma unroll
    for (int mt = 0; mt < 4; ++mt)
        #pragma unroll
        for (int r = 0; r < 4; ++r) {
            int rr = 128 * r + 16 * wv + 4 * mt + lK;
            bias4[mt][r] = b_ih[rr] + b_hh[rr];
        }
    __syncthreads();

    // ---- recurrent loop: NO gather. Lane owns cell j* = 16wv+4(lN>>2)+lK,
    // seq lN&3; gates come from acc[lN>>2][0..3] via 4-way register select.
    const int hoffR = (lN & 3) * HSTR;      // B-frag h read (real seq row)
    const ushort* xrow = xh + (lN & 3) * XSTR + (lK & 1) * 8;
    const int  mtSel  = lN >> 2;
    const bool selLo  = (mtSel < 2);
    const bool selOdd = (mtSel & 1);
    const bool sel3   = (mtSel == 3);
    const int hwoff = (lN & 3) * HSTR + 16 * wv + 4 * (lN >> 2) + lK;
    ushort* repL = rep + ((size_t)(nb + (lN & 3)) * T_) * H_
                       + 16 * wv + 4 * (lN >> 2) + lK;
    const f32x4 zc = {0.f, 0.f, 0.f, 0.f};
    float cst = 0.f;
    #pragma unroll 1
    for (int tb = 0; tb < 16; ++tb) {
        s16x8 bx0 = *(const s16x8*)(xrow + (4 * tb + 0) * 16);
        s16x8 bx1 = *(const s16x8*)(xrow + (4 * tb + 1) * 16);
        s16x8 bx2 = *(const s16x8*)(xrow + (4 * tb + 2) * 16);
        s16x8 bx3 = *(const s16x8*)(xrow + (4 * tb + 3) * 16);
        #pragma unroll
        for (int u = 0; u < 4; ++u) {
            const int t = 4 * tb + u;
            s16x8 bx = (u == 0) ? bx0 : (u == 1) ? bx1 : (u == 2) ? bx2 : bx3;

            const ushort* hh = (u & 1) ? hB : hA;     // compile-time select
            s16x8 bh0 = *(const s16x8*)(hh + hoffR + 0 * 32 + lK * 8);
            s16x8 bh1 = *(const s16x8*)(hh + hoffR + 1 * 32 + lK * 8);
            s16x8 bh2 = *(const s16x8*)(hh + hoffR + 2 * 32 + lK * 8);
            s16x8 bh3 = *(const s16x8*)(hh + hoffR + 3 * 32 + lK * 8);

            // two parallel chains per tile: (wif->ks0->ks1) || (ks2->ks3)
            f32x4 a0 = MFMA16(wif[0], bx, bias4[0]);
            f32x4 a1 = MFMA16(wif[1], bx, bias4[1]);
            f32x4 a2 = MFMA16(wif[2], bx, bias4[2]);
            f32x4 a3 = MFMA16(wif[3], bx, bias4[3]);
            a0 = MFMA16(wf[0][0], bh0, a0); a1 = MFMA16(wf[1][0], bh0, a1);
            a2 = MFMA16(wf[2][0], bh0, a2); a3 = MFMA16(wf[3][0], bh0, a3);
            a0 = MFMA16(wf[0][1], bh1, a0); a1 = MFMA16(wf[1][1], bh1, a1);
            a2 = MFMA16(wf[2][1], bh1, a2); a3 = MFMA16(wf[3][1], bh1, a3);
            f32x4 d0 = MFMA16(wf[0][2], bh2, zc);
            f32x4 d1 = MFMA16(wf[1][2], bh2, zc);
            f32x4 d2 = MFMA16(wf[2][2], bh2, zc);
            f32x4 d3 = MFMA16(wf[3][2], bh2, zc);
            d0 = MFMA16(wf[0][3], bh3, d0); d1 = MFMA16(wf[1][3], bh3, d1);
            d2 = MFMA16(wf[2][3], bh3, d2); d3 = MFMA16(wf[3][3], bh3, d3);

            // 4-way register select by mtSel (3 cndmask per gate), fp32
            float g0s, g1s, g2s, g3s;
            {
                float p0 = a0[0] + d0[0], p1 = a1[0] + d1[0];
                float p2 = a2[0] + d2[0], p3 = a3[0] + d3[0];
                g0s = selLo ? (selOdd ? p1 : p0) : (sel3 ? p3 : p2);
                p0 = a0[1] + d0[1]; p1 = a1[1] + d1[1];
                p2 = a2[1] + d2[1]; p3 = a3[1] + d3[1];
                g1s = selLo ? (selOdd ? p1 : p0) : (sel3 ? p3 : p2);
                p0 = a0[2] + d0[2]; p1 = a1[2] + d1[2];
                p2 = a2[2] + d2[2]; p3 = a3[2] + d3[2];
                g2s = selLo ? (selOdd ? p1 : p0) : (sel3 ? p3 : p2);
                p0 = a0[3] + d0[3]; p1 = a1[3] + d1[3];
                p2 = a2[3] + d2[3]; p3 = a3[3] + d3[3];
                g3s = selLo ? (selOdd ? p1 : p0) : (sel3 ? p3 : p2);
            }

            // ONE cell update per lane (fp32 preacts)
            float ii = sigmoidf_(g0s);
            float ff = sigmoidf_(g1s);
            float gt = tanhf_(g2s);
            float oo = sigmoidf_(g3s);
            float c  = ff * cst + ii * gt;
            cst = c;
            ushort hb = f2h(oo * tanhf_(c));

            ushort* hw = (u & 1) ? hA : hB;           // write the OTHER buffer
            hw[hwoff] = hb;                           // 2B LDS write
            repL[(size_t)t * H_] = hb;                // 2B global (floats to L2)
            BAR_LDS();                                // LDS-only barrier
        }
    }

    // ================= epilogue (4 seqs in this block) =================
    // E0: stage w1 (fp16, stride 140) + wa/ba  (recurrence LDS dead)
    for (int idx = tid; idx < 128 * 128; idx += 512) {
        int o = idx >> 7, k = idx & 127;
        w1h[o * 140 + k] = f2h(w1[idx]);
    }
    if (tid < 128) wab[tid] = wa[tid];
    if (tid == 128) wab[128] = ba[0];
    __syncthreads();   // FULL barrier: drains vmcnt(0) -> rep stores visible

    // E1: a2[s][o] = h63 @ w2^T + b1 + b2  (wave 0; A rows >=4 dup of row&3)
    if (wv == 0) {
        s16x8 ar[4];
        #pragma unroll
        for (int ks = 0; ks < 4; ++ks)
            ar[ks] = *(const s16x8*)(rep + ((size_t)(nb + (lN & 3)) * T_ + 63) * H_ + ks * 32 + lK * 8);
        #pragma unroll
        for (int nt = 0; nt < 8; ++nt) {
            f32x4 acc = {0.f,0.f,0.f,0.f};
            const int o = 16 * nt + lN;
            #pragma unroll
            for (int ks = 0; ks < 4; ++ks) {
                const float4* p = (const float4*)(w2 + (size_t)o * 128 + ks * 32 + lK * 8);
                float4 v0 = p[0], v1 = p[1];
                s16x8 bb;
                bb[0]=(short)f2h(v0.x); bb[1]=(short)f2h(v0.y); bb[2]=(short)f2h(v0.z); bb[3]=(short)f2h(v0.w);
                bb[4]=(short)f2h(v1.x); bb[5]=(short)f2h(v1.y); bb[6]=(short)f2h(v1.z); bb[7]=(short)f2h(v1.w);
                acc = MFMA16(ar[ks], bb, acc);
            }
            float bb12 = b1[o] + b2[o];
            #pragma unroll
            for (int r = 0; r < 4; ++r)
                a2s[(4 * lK + r) * 128 + o] = acc[r] + bb12;   // seq = 4lK+r
        }
    }
    __syncthreads();

    // E2: logits[t] = sum_o wa[o]*tanh((rep @ w1^T)[t][o] + a2[o])
    // 2 waves per seq: seq = wv>>1, mt = (wv&1)*2 + mtl
    {
        const int seq = wv >> 1;
        #pragma unroll 1
        for (int mtl = 0; mtl < 2; ++mtl) {
            const int mt = (wv & 1) * 2 + mtl;
            s16x8 ar[4];
            #pragma unroll
            for (int ks = 0; ks < 4; ++ks)
                ar[ks] = *(const s16x8*)(rep + ((size_t)(nb + seq) * T_ + 16 * mt + lN) * H_ + ks * 32 + lK * 8);
            float part[4] = {0.f,0.f,0.f,0.f};
            #pragma unroll
            for (int nt = 0; nt < 8; ++nt) {
                f32x4 acc = {0.f,0.f,0.f,0.f};
                #pragma unroll
                for (int ks = 0; ks < 4; ++ks)
                    acc = MFMA16(ar[ks],
                                 *(const s16x8*)(w1h + (lN + 16 * nt) * 140 + ks * 32 + lK * 8),
                                 acc);
                const int o = lN + 16 * nt;
                const float wao = wab[o];
                const float a2o = a2s[seq * 128 + o];
                #pragma unroll
                for (int r = 0; r < 4; ++r)
                    part[r] += wao * tanhf_(acc[r] + a2o);
            }
            #pragma unroll
            for (int r = 0; r < 4; ++r) {
                part[r] += __shfl_xor(part[r], 1);
                part[r] += __shfl_xor(part[r], 2);
                part[r] += __shfl_xor(part[r], 4);
                part[r] += __shfl_xor(part[r], 8);
            }
            if (lN == 0) {
                float4 st; st.x = part[0]; st.y = part[1]; st.z = part[2]; st.w = part[3];
                *(float4*)(logitb + seq * 64 + 16 * mt + 4 * lK) = st;  // t = 16mt+4lK+r
            }
        }
    }
    __syncthreads();

    // E3: softmax over 64 logits, seq = wv (waves 0..3)
    if (wv < NB_) {
        const int seq = wv;
        float vl = logitb[seq * 64 + lane] + wab[128];
        float m = vl;
        #pragma unroll
        for (int off = 1; off < 64; off <<= 1) m = fmaxf(m, __shfl_xor(m, off));
        float e = __expf(vl - m);
        float ss = e;
        #pragma unroll
        for (int off = 1; off < 64; off <<= 1) ss += __shfl_xor(ss, off);
        alph[seq * 64 + lane] = e / ss;
    }
    __syncthreads();

    // E4: stock_rep[s][h] = sum_t alpha * rep  (fp32, into a2s alias)
    {
        const int s = tid >> 7, o = tid & 127;     // 1 element per thread
        float acc = 0.f;
        const ushort* rp = rep + (size_t)(nb + s) * T_ * H_ + o;
        #pragma unroll 8
        for (int t = 0; t < T_; ++t)
            acc += alph[s * 64 + t] * h2f(rp[(size_t)t * H_]);
        __syncthreads();                           // a2s readers (E2) done
        a2s[s * 128 + o] = acc;
    }
    __syncthreads();

    // E5: q,k,v = sr @ W^T + b  (fp32 VALU; one seq per thread-group)
    {
        const float* sr = a2s;
        const int o = tid & 127, sg = tid >> 7;    // sg = seq 0..3
        float aq = 0.f, ak = 0.f, av = 0.f;
        for (int k = 0; k < 128; k += 4) {
            float4 q4 = *(const float4*)(wq  + (size_t)o * 128 + k);
            float4 k4 = *(const float4*)(wk  + (size_t)o * 128 + k);
            float4 v4 = *(const float4*)(wvm + (size_t)o * 128 + k);
            float4 s4 = *(const float4*)(sr + sg * 128 + k);
            aq += q4.x*s4.x + q4.y*s4.y + q4.z*s4.z + q4.w*s4.w;
            ak += k4.x*s4.x + k4.y*s4.y + k4.z*s4.z + k4.w*s4.w;
            av += v4.x*s4.x + v4.y*s4.y + v4.z*s4.z + v4.w*s4.w;
        }
        qout[(size_t)(nb + sg) * H_ + o] = aq + bq[o];
        kout[(size_t)(nb + sg) * H_ + o] = ak + bk[o];
        vout[(size_t)(nb + sg) * H_ + o] = av + bv[o];
    }
}

// Cross-asset attention: one block per (b, m) query row, 256 threads. fp32 out.
__global__ __launch_bounds__(256, 4)
void caan(const float* __restrict__ qb, const float* __restrict__ kb,
          const float* __restrict__ vb, const float* __restrict__ ww,
          const float* __restrict__ bw, float* __restrict__ out)
{
    __shared__ alignas(16) float qs[H_];
    __shared__ alignas(16) float sc[512];
    __shared__ alignas(16) float red[8];
    __shared__ alignas(16) float pv[2][H_];

    const int n   = blockIdx.x;
    const int b   = n >> 9;
    const int tid = threadIdx.x;

    if (tid < H_) qs[tid] = qb[n * H_ + tid];
    __syncthreads();

    const float scale = 0.08838834764831845f;  // 1/sqrt(128)
    float s0raw = 0.f, s1raw = 0.f;
    #pragma unroll
    for (int r = 0; r < 2; ++r) {
        const int j = tid + r * 256;
        const float4* kp = (const float4*)(kb + (size_t)(b * 512 + j) * H_);
        const float4* qp = (const float4*)qs;
        float c0=0.f,c1=0.f,c2=0.f,c3=0.f;
        #pragma unroll
        for (int i = 0; i < 32; ++i) {
            float4 kv = kp[i], qv = qp[i];
            c0 += kv.x*qv.x; c1 += kv.y*qv.y; c2 += kv.z*qv.z; c3 += kv.w*qv.w;
        }
        float sres = ((c0 + c1) + (c2 + c3)) * scale;
        if (r == 0) s0raw = sres; else s1raw = sres;
    }

    float m = fmaxf(s0raw, s1raw);
    #pragma unroll
    for (int off = 1; off < 64; off <<= 1) m = fmaxf(m, __shfl_xor(m, off));
    if ((tid & 63) == 0) red[tid >> 6] = m;
    __syncthreads();
    m = fmaxf(fmaxf(red[0], red[1]), fmaxf(red[2], red[3]));
    float e0 = __expf(s0raw - m), e1 = __expf(s1raw - m);
    sc[tid] = e0; sc[tid + 256] = e1;
    float lsum = e0 + e1;
    #pragma unroll
    for (int off = 1; off < 64; off <<= 1) lsum += __shfl_xor(lsum, off);
    if ((tid & 63) == 0) red[4 + (tid >> 6)] = lsum;
    __syncthreads();
    const float inv = 1.0f / ((red[4] + red[5]) + (red[6] + red[7]));

    const int o  = tid & (H_ - 1);
    const int jh = tid >> 7;
    const float* vp = vb + (size_t)(b * 512 + jh * 256) * H_ + o;
    float a0=0.f,a1=0.f,a2=0.f,a3=0.f;
    for (int j = 0; j < 256; j += 4) {
        a0 += sc[jh*256 + j + 0] * vp[(size_t)(j + 0) * H_];
        a1 += sc[jh*256 + j + 1] * vp[(size_t)(j + 1) * H_];
        a2 += sc[jh*256 + j + 2] * vp[(size_t)(j + 2) * H_];
        a3 += sc[jh*256 + j + 3] * vp[(size_t)(j + 3) * H_];
    }
    pv[jh][o] = (a0 + a1) + (a2 + a3);
    __syncthreads();
    if (tid < H_) {
        float s = (pv[0][tid] + pv[1][tid]) * inv * ww[tid];
        s += __shfl_xor(s, 1);  s += __shfl_xor(s, 2);  s += __shfl_xor(s, 4);
        s += __shfl_xor(s, 8);  s += __shfl_xor(s, 16); s += __shfl_xor(s, 32);
        if ((tid & 63) == 0) red[tid >> 6] = s;
    }
    __syncthreads();
    if (tid == 0) out[n] = red[0] + red[1] + bw[0];
}

extern "C" void kernel_launch(void* const* d_in, const int* in_sizes, int n_in,
                              void* d_out, int out_size, void* d_ws, size_t ws_size,
                              hipStream_t stream)
{
    const float* x    = (const float*)d_in[0];
    const float* W_ih = (const float*)d_in[1];
    const float* W_hh = (const float*)d_in[2];
    const float* b_ih = (const float*)d_in[3];
    const float* b_hh = (const float*)d_in[4];
    const float* w1   = (const float*)d_in[5];
    const float* b1   = (const float*)d_in[6];
    const float* w2   = (const float*)d_in[7];
    const float* b2   = (const float*)d_in[8];
    const float* wa   = (const float*)d_in[9];
    const float* ba   = (const float*)d_in[10];
    const float* wq   = (const float*)d_in[11];
    const float* bq   = (const float*)d_in[12];
    const float* wk   = (const float*)d_in[13];
    const float* bk   = (const float*)d_in[14];
    const float* wv   = (const float*)d_in[15];
    const float* bv   = (const float*)d_in[16];
    const float* ww   = (const float*)d_in[17];
    const float* bw   = (const float*)d_in[18];

    float* ws   = (float*)d_ws;
    float* qbuf = ws;                              // 1024*128 f32
    float* kbuf = ws + (size_t)NSEQ_ * H_;
    float* vbuf = ws + (size_t)2 * NSEQ_ * H_;
    ushort* rep = (ushort*)(ws + (size_t)3 * NSEQ_ * H_);        // 16 MB fp16

    alphastock_main<<<NBLK_, 512, 0, stream>>>(x, W_ih, W_hh, b_ih, b_hh,
                                               w1, b1, w2, b2, wa, ba,
                                               wq, bq, wk, bk, wv, bv,
                                               rep, qbuf, kbuf, vbuf);
    caan<<<NSEQ_, 256, 0, stream>>>(qbuf, kbuf, vbuf, ww, bw, (float*)d_out);
}